// Round 11
// baseline (399.316 us; speedup 1.0000x reference)
//
#include <hip/hip_runtime.h>

#define NS 6
#define NXD 3
#define NC 8
#define NR 64
#define NB 36          // S * 2 * XD
#define NPOINTS 262144
#define OUTD 288       // C * NB
#define PTS 16         // points per block; block = 16 pts * 16 thr/pt = 256

#define PXU_TOTAL (NB * 64 * 64 * 4)  // 589,824 uints (2.36 MB int4 table)
#define F1B_TOTAL (NB * NC * 66)      //  19,008 bytes (int8 f1 table, 66 = 64+dup+pad)
#define F1B_UINTS (F1B_TOTAL / 4)     //   4,752

#define QS4 1024.0f            // 2^10 scale for int4 px corners
#define QS8 32768.0f           // 2^15 scale for int8 f1
#define PRODSCALE 0x1p-25f     // 2^-10 * 2^-15

__device__ __forceinline__ unsigned f2q4(float f) {
    float q = rintf(f * QS4);
    q = fminf(fmaxf(q, -7.0f), 7.0f);
    return (unsigned)((int)q) & 0xFu;
}

// Merged build:
//  tid < PXU_TOTAL: pxu [NB][64][64][4] uint — 2 channels x 4 int4 corners
//    (ch 2c2 in bits 0..15 {v00,v01,v10,v11}, ch 2c2+1 in bits 16..31).
//  else: f1b [NB][NC][66] int8 = round(2^15 * 0.5*(F[b][c][ys][31]+[32])),
//    ys = min(y,63) (row 64 duplicates 63 for the y0+1 read; 65 = pad).
__global__ void build_tables(const float* __restrict__ F,
                             const float* __restrict__ F2,
                             unsigned* __restrict__ pxu,
                             signed char* __restrict__ f1b)
{
    int tid = blockIdx.x * 256 + threadIdx.x;
    if (tid < PXU_TOTAL) {
        int c2 = tid & 3;
        int xx = (tid >> 2) & 63;
        int y  = (tid >> 8) & 63;
        int b  = tid >> 14;
        int x1 = xx < 63 ? xx + 1 : 63;
        int y1 = y  < 63 ? y  + 1 : 63;
        unsigned acc = 0;
        #pragma unroll
        for (int j = 0; j < 2; ++j) {
            int c = 2 * c2 + j;
            const float* img = F2 + (size_t)(b * NC + c) * (NR * NR);
            unsigned q00 = f2q4(img[y  * NR + xx]);
            unsigned q01 = f2q4(img[y  * NR + x1]);
            unsigned q10 = f2q4(img[y1 * NR + xx]);
            unsigned q11 = f2q4(img[y1 * NR + x1]);
            acc |= (q00 | (q01 << 4) | (q10 << 8) | (q11 << 12)) << (16 * j);
        }
        pxu[tid] = acc;
    } else {
        int t2 = tid - PXU_TOTAL;
        if (t2 >= F1B_TOTAL) return;
        int y    = t2 % 66;
        int rest = t2 / 66;
        int c    = rest & 7;
        int b    = rest >> 3;
        int ys   = y < 64 ? y : 63;
        const float* img = F + (size_t)(b * NC + c) * NR * NR;
        float f1 = (img[ys * NR + 31] + img[ys * NR + 32]) * (0.5f * QS8);
        float q  = fminf(fmaxf(rintf(f1), -127.0f), 127.0f);
        f1b[t2] = (signed char)(int)q;
    }
}

// Thread = (point u, half h, channel c): 16 threads/point, PTS=16.
// f1 moved from global gathers into a 19 KB LDS table (ds_read_i8, no TCP
// line-requests) — deletes HALF of all cache-line requests. px line-touch
// count per (point,b) is invariant to the remap. LDS total 37.5 KB ->
// 4 blocks/CU = 16 waves/CU (same occupancy as R10).
__global__ __launch_bounds__(256, 4) void encode_kernel(
    const float* __restrict__ x,
    const unsigned* __restrict__ pxu,
    const unsigned* __restrict__ f1g,   // f1b viewed as uints for prologue
    float* __restrict__ out)
{
    __shared__ float stage[PTS * 289];      // 18,496 B
    __shared__ unsigned f1li[F1B_UINTS];    // 19,008 B
    const signed char* f1c = (const signed char*)f1li;

    const int t = threadIdx.x;
    // prologue: broadcast-load the 19 KB f1 table into LDS (L2-resident src)
    #pragma unroll
    for (int i = 0; i < 19; ++i) {
        int idx = t + i * 256;
        if (idx < F1B_UINTS) f1li[idx] = f1g[idx];
    }

    const int c = t & 7;                  // channel
    const int h = (t >> 3) & 1;           // b-half: b in [18h, 18h+18)
    const int u = t >> 4;                 // point within tile [0,16)
    const int n = blockIdx.x * PTS + u;

    const float xv0 = x[3 * n + 0];
    const float xv1 = x[3 * n + 1];
    const float xv2 = x[3 * n + 2];

    const float scb = h ? 8.0f : 1.0f;    // 2^(3h)
    const float a0v = xv0 * scb, a1v = xv1 * scb, a2v = xv2 * scb;

    const int hb = 18 * h;
    const unsigned* pxp = pxu + hb * 16384 + (c >> 1);  // + bloc*16384 + (yy*64+xx)*4
    const int f1base = (hb * 8 + c) * 66;               // + bloc*8*66 + y0
    const int sh = (c & 1) << 4;                        // 0 or 16
    float* stg = &stage[u * 289 + c * 36 + hb];         // + bloc

    __syncthreads();                      // f1 LDS table ready

    #pragma unroll
    for (int gg = 0; gg < 6; ++gg) {      // group g = 6h + gg; p = gg&1
        const float m = (float)(1 << (gg >> 1));   // 1,1,2,2,4,4 compile-time
        float l0, l1, l2;
        if ((gg & 1) == 0) {
            l0 = __sinf(a0v * m); l1 = __sinf(a1v * m); l2 = __sinf(a2v * m);
        } else {
            l0 = __cosf(a0v * m); l1 = __cosf(a1v * m); l2 = __cosf(a2v * m);
        }
        #pragma unroll
        for (int k = 0; k < 3; ++k) {
            const int bloc = 3 * gg + k;  // local b in [0,18), compile-time
            // pairs = [[1,2],[2,0],[0,1]]
            float gy1 = (k == 0) ? l0 : (k == 1) ? l1 : l2;
            float ga  = (k == 0) ? l1 : (k == 1) ? l2 : l0;
            float gb  = (k == 0) ? l2 : (k == 1) ? l0 : l1;

            // sin/cos in [-1,1] => fma(.,31.5,31.5) in [0,63]; keep lower
            // guard only (floor(-eps) would index out of the table).
            float fy  = fmaxf(__builtin_fmaf(gy1, 31.5f, 31.5f), 0.0f);
            float fy0 = floorf(fy);
            float wy  = fy - fy0;
            int   y0  = (int)fy0;

            // fs: 1-D lerp from LDS int8 (wx=0.5 folded; y=64 row = dup 63)
            float a0 = (float)f1c[f1base + bloc * 528 + y0];
            float a1 = (float)f1c[f1base + bloc * 528 + y0 + 1];
            float fsv = __builtin_fmaf(a1 - a0, wy, a0);   // x 2^-15 real

            // fs2: bilinear, 4 int4 corners from ONE dword gather
            float fx2  = fmaxf(__builtin_fmaf(ga, 31.5f, 31.5f), 0.0f);
            float fy2  = fmaxf(__builtin_fmaf(gb, 31.5f, 31.5f), 0.0f);
            float fx20 = floorf(fx2);
            float fy20 = floorf(fy2);
            float wx2  = fx2 - fx20;
            float wy2  = fy2 - fy20;
            int   xx   = (int)fx20;
            int   yy   = (int)fy20;
            unsigned w = pxp[bloc * 16384 + (yy * 64 + xx) * 4];
            unsigned wh = sh ? (w >> 16) : w;   // this channel's 16 bits
            float v00 = (float)((int)(wh << 28) >> 28);
            float v01 = (float)((int)(wh << 24) >> 28);
            float v10 = (float)((int)(wh << 20) >> 28);
            float v11 = (float)((int)(wh << 16) >> 28);
            float tp = __builtin_fmaf(v01 - v00, wx2, v00);
            float bt = __builtin_fmaf(v11 - v10, wx2, v10);
            float fs2v = __builtin_fmaf(bt - tp, wy2, tp); // x 2^-10 real

            // real = fsv*fs2v*2^-25 + latent
            stg[bloc] = __builtin_fmaf(fsv * fs2v, PRODSCALE, gy1);
        }
    }
    __syncthreads();

    // coalesced NONTEMPORAL writeback: block region = PTS*288 = 4608 floats
    float* ob = out + (size_t)blockIdx.x * (PTS * OUTD);
    int uu = 0;            // t < 288 always
    int v  = t;
    #pragma unroll
    for (int r = 0; r < 18; ++r) {
        __builtin_nontemporal_store(stage[uu * 289 + v], &ob[t + r * 256]);
        v += 256;
        if (v >= 288) { v -= 288; ++uu; }
    }
}

extern "C" void kernel_launch(void* const* d_in, const int* in_sizes, int n_in,
                              void* d_out, int out_size, void* d_ws, size_t ws_size,
                              hipStream_t stream)
{
    const float* x  = (const float*)d_in[0];
    const float* F  = (const float*)d_in[1];
    const float* F2 = (const float*)d_in[2];
    float* out = (float*)d_out;

    unsigned* pxu     = (unsigned*)d_ws;             // 2,359,296 B
    signed char* f1b  = (signed char*)(pxu + PXU_TOTAL);  // 19,008 B

    build_tables<<<(PXU_TOTAL + F1B_TOTAL + 255) / 256, 256, 0, stream>>>(F, F2, pxu, f1b);
    encode_kernel<<<NPOINTS / PTS, 256, 0, stream>>>(x, pxu, (const unsigned*)f1b, out);
}

// Round 14
// 355.067 us; speedup vs baseline: 1.1246x; 1.1246x over previous
//
#include <hip/hip_runtime.h>

#define NS 6
#define NXD 3
#define NC 8
#define NR 64
#define NB 36          // S * 2 * XD
#define NPOINTS 262144
#define OUTD 288       // C * NB
#define PTS 16         // points per block; 16 threads/point -> 256 threads

#define PXU_TOTAL (NB * 64 * 64 * 4)  // 589,824 uints (2.36 MB int4 table)
#define F1TOTAL   (NB * 64 * NC)      //  18,432 uints (bf16-pair f1 table)

__device__ __forceinline__ unsigned short f2bf(float f) {
    unsigned u = __float_as_uint(f);
    unsigned r = u + 0x7fffu + ((u >> 16) & 1u);   // round-to-nearest-even
    return (unsigned short)(r >> 16);
}
__device__ __forceinline__ unsigned pack2(float a, float b) {
    return (unsigned)f2bf(a) | ((unsigned)f2bf(b) << 16);
}

#define QS4   1024.0f           // 2^10 fixed-point scale for int4 corners
#define QINV4 (1.0f / 1024.0f)

__device__ __forceinline__ unsigned f2q4(float f) {
    float q = rintf(f * QS4);
    q = fminf(fmaxf(q, -7.0f), 7.0f);
    return (unsigned)((int)q) & 0xFu;
}

// Merged table build — identical to R10 (best measured):
//   tid < PXU_TOTAL:  pxu [NB][64][64][4] uint — 2 channels x 4 int4 corners
//   else:             f1q [NB][64][NC] uint = bf16 pair {f1[y],f1[y+1]} * 2^-10
__global__ void build_tables(const float* __restrict__ F,
                             const float* __restrict__ F2,
                             unsigned* __restrict__ pxu,
                             unsigned* __restrict__ f1q)
{
    int tid = blockIdx.x * 256 + threadIdx.x;
    if (tid < PXU_TOTAL) {
        int c2 = tid & 3;
        int xx = (tid >> 2) & 63;
        int y  = (tid >> 8) & 63;
        int b  = tid >> 14;
        int x1 = xx < 63 ? xx + 1 : 63;
        int y1 = y  < 63 ? y  + 1 : 63;
        unsigned acc = 0;
        #pragma unroll
        for (int j = 0; j < 2; ++j) {
            int c = 2 * c2 + j;
            const float* img = F2 + (size_t)(b * NC + c) * (NR * NR);
            unsigned q00 = f2q4(img[y  * NR + xx]);
            unsigned q01 = f2q4(img[y  * NR + x1]);
            unsigned q10 = f2q4(img[y1 * NR + xx]);
            unsigned q11 = f2q4(img[y1 * NR + x1]);
            acc |= (q00 | (q01 << 4) | (q10 << 8) | (q11 << 12)) << (16 * j);
        }
        pxu[tid] = acc;
    } else {
        int t2 = tid - PXU_TOTAL;
        if (t2 >= F1TOTAL) return;
        int c = t2 & 7;
        int y = (t2 >> 3) & 63;
        int b = t2 >> 9;
        const float* img = F + (size_t)(b * NC + c) * NR * NR;
        const float sc = 0.5f * QINV4;
        float a = sc * (img[y * NR + 31] + img[y * NR + 32]);
        int y1 = y < 63 ? y + 1 : 63;
        float bb = sc * (img[y1 * NR + 31] + img[y1 * NR + 32]);
        f1q[t2] = pack2(a, bb);
    }
}

// Thread = (point u, e, h, c2): 16 threads/point, 9 blocs each.
// Occupancy experiment (model B: in-flight lines scale with waves/CU):
// stage 18,496 B + shallow 9-bloc unroll -> natural VGPR ~80-90 ->
// floor(512/VGPR) = 5-6 waves/SIMD = 20-24 waves/CU (R10 was 16).
// NOTE: no forced min-waves bound — R12/R13's __launch_bounds__(256,6)
// (85-VGPR cap under this unroll) is the prime suspect for the two
// container failures; plain (256) removes the allocator coercion.
// Runtime sin/cos parity branch-free: cos(x) = sin(x + pi/2).
__global__ __launch_bounds__(256) void encode_kernel(
    const float* __restrict__ x,
    const unsigned* __restrict__ pxu,
    const unsigned* __restrict__ f1q,
    float* __restrict__ out)
{
    __shared__ float stage[PTS * 289];    // 18,496 B; LDS allows 8 blocks/CU
    const int t  = threadIdx.x;
    const int c2 = t & 3;                 // channel pair
    const int h  = (t >> 2) & 1;          // b-half: b in [18h, 18h+18)
    const int e  = (t >> 3) & 1;          // bloc-quarter: bloc in [9e, 9e+9)
    const int u  = t >> 4;                // point within tile [0,16)
    const int n  = blockIdx.x * PTS + u;

    const float xv0 = x[3 * n + 0];
    const float xv1 = x[3 * n + 1];
    const float xv2 = x[3 * n + 2];

    const float scb = h ? 8.0f : 1.0f;    // 2^(3h)
    const float a0v = xv0 * scb, a1v = xv1 * scb, a2v = xv2 * scb;

    const int hb = 18 * h;
    const int eb = 9 * e;
    const unsigned* f1p = f1q + hb * 512 + 2 * c2;   // + bloc*512 + y0*8
    const unsigned* pxp = pxu + hb * 16384 + c2;     // + bloc*16384 + (yy*64+xx)*4
    float* stg = &stage[u * 289 + (2 * c2) * 36 + hb];

    #pragma unroll
    for (int j = 0; j < 3; ++j) {         // gg = 3e + j; p = (e+j)&1
        const float m  = (float)(1 << ((3 * e + j) >> 1));
        const float ph = ((e + j) & 1) ? 1.5707963267948966f : 0.0f;
        float l0 = __sinf(__builtin_fmaf(a0v, m, ph));
        float l1 = __sinf(__builtin_fmaf(a1v, m, ph));
        float l2 = __sinf(__builtin_fmaf(a2v, m, ph));
        #pragma unroll
        for (int k = 0; k < 3; ++k) {
            const int bloc = eb + 3 * j + k;   // [0,18)
            // pairs = [[1,2],[2,0],[0,1]]
            float gy1 = (k == 0) ? l0 : (k == 1) ? l1 : l2;
            float ga  = (k == 0) ? l1 : (k == 1) ? l2 : l0;
            float gb  = (k == 0) ? l2 : (k == 1) ? l0 : l1;

            // sin in [-1,1] => fma(.,31.5,31.5) in [0,63]; keep lower guard
            // only (floor(-eps) would index out of the table).
            float fy  = fmaxf(__builtin_fmaf(gy1, 31.5f, 31.5f), 0.0f);
            float fy0 = floorf(fy);
            float wy  = fy - fy0;
            int   y0  = (int)fy0;
            uint2 pr  = *(const uint2*)(f1p + bloc * 512 + y0 * 8);

            float fx2  = fmaxf(__builtin_fmaf(ga, 31.5f, 31.5f), 0.0f);
            float fy2  = fmaxf(__builtin_fmaf(gb, 31.5f, 31.5f), 0.0f);
            float fx20 = floorf(fx2);
            float fy20 = floorf(fy2);
            float wx2  = fx2 - fx20;
            float wy2  = fy2 - fy20;
            int   xx   = (int)fx20;
            int   yy   = (int)fy20;
            unsigned w = pxp[bloc * 16384 + (yy * 64 + xx) * 4];

            // channel 2c2: nibbles 0..3
            {
                float a0 = __uint_as_float(pr.x << 16);
                float a1 = __uint_as_float(pr.x & 0xffff0000u);
                float fsv = __builtin_fmaf(a1 - a0, wy, a0);
                float v00 = (float)((int)(w << 28) >> 28);
                float v01 = (float)((int)(w << 24) >> 28);
                float v10 = (float)((int)(w << 20) >> 28);
                float v11 = (float)((int)(w << 16) >> 28);
                float tp = __builtin_fmaf(v01 - v00, wx2, v00);
                float bt = __builtin_fmaf(v11 - v10, wx2, v10);
                float fs2v = __builtin_fmaf(bt - tp, wy2, tp);
                stg[bloc] = __builtin_fmaf(fsv, fs2v, gy1);
            }
            // channel 2c2+1: nibbles 4..7
            {
                float a0 = __uint_as_float(pr.y << 16);
                float a1 = __uint_as_float(pr.y & 0xffff0000u);
                float fsv = __builtin_fmaf(a1 - a0, wy, a0);
                float v00 = (float)((int)(w << 12) >> 28);
                float v01 = (float)((int)(w <<  8) >> 28);
                float v10 = (float)((int)(w <<  4) >> 28);
                float v11 = (float)((int)w         >> 28);
                float tp = __builtin_fmaf(v01 - v00, wx2, v00);
                float bt = __builtin_fmaf(v11 - v10, wx2, v10);
                float fs2v = __builtin_fmaf(bt - tp, wy2, tp);
                stg[36 + bloc] = __builtin_fmaf(fsv, fs2v, gy1);
            }
        }
    }
    __syncthreads();

    // coalesced NONTEMPORAL writeback: block region = PTS*288 = 4608 floats
    // (nt keeps the 302 MB output stream from evicting the gather tables:
    //  measured -18us in R9).
    float* ob = out + (size_t)blockIdx.x * (PTS * OUTD);
    int uu = 0;            // t < 288 always
    int v  = t;
    #pragma unroll
    for (int r = 0; r < 18; ++r) {
        __builtin_nontemporal_store(stage[uu * 289 + v], &ob[t + r * 256]);
        v += 256;
        if (v >= 288) { v -= 288; ++uu; }
    }
}

extern "C" void kernel_launch(void* const* d_in, const int* in_sizes, int n_in,
                              void* d_out, int out_size, void* d_ws, size_t ws_size,
                              hipStream_t stream)
{
    const float* x  = (const float*)d_in[0];
    const float* F  = (const float*)d_in[1];
    const float* F2 = (const float*)d_in[2];
    float* out = (float*)d_out;

    unsigned* pxu = (unsigned*)d_ws;                 // 2,359,296 B
    unsigned* f1q = pxu + PXU_TOTAL;                 //    73,728 B

    build_tables<<<(PXU_TOTAL + F1TOTAL + 255) / 256, 256, 0, stream>>>(F, F2, pxu, f1q);
    encode_kernel<<<NPOINTS / PTS, 256, 0, stream>>>(x, pxu, f1q, out);
}